// Round 2
// baseline (1337.012 us; speedup 1.0000x reference)
//
#include <hip/hip_runtime.h>
#include <hip/hip_bf16.h>

#define N_NODES 50000
#define N_EDGES 800000
#define IN_F 512
#define HID 256
#define HEADS 8
#define DHEAD 32
#define N_CLS 40
#define NCLS_PAD 64

typedef __bf16 bf16x8 __attribute__((ext_vector_type(8)));
typedef float f32x4 __attribute__((ext_vector_type(4)));

// read element i of a raw array that is bf16 if isbf else f32
__device__ __forceinline__ float ldflag(const void* p, long long i, int isbf) {
  return isbf ? __bfloat162float(((const __hip_bfloat16*)p)[i])
              : ((const float*)p)[i];
}

// ---------------- dtype detection ----------------
// If raw data is f32, its low 16-bit halves (decoded as bf16) have uniform-random
// exponent fields -> ~22% of all halves have exp>=0x90 (|x|>=2^17). Genuine bf16
// N(0,1) data never does. One block, writes flag: 1 = bf16 inputs, 0 = f32 inputs.
__global__ void k_detect(const unsigned short* __restrict__ raw, int* __restrict__ flag) {
  __shared__ int cnt[256];
  int t = threadIdx.x;
  int c = 0;
  for (int i = t; i < 8192; i += 256) {
    int e = (raw[i] >> 7) & 0xFF;
    if (e >= 0x90) c++;
  }
  cnt[t] = c;
  __syncthreads();
  for (int s = 128; s; s >>= 1) {
    if (t < s) cnt[t] += cnt[t + s];
    __syncthreads();
  }
  if (t == 0) *flag = (cnt[0] > 64) ? 0 : 1;
}

// ---------------- CSR build (by dst) ----------------
__global__ void k_hist(const int* __restrict__ dst, int* __restrict__ cnt) {
  int e = blockIdx.x * blockDim.x + threadIdx.x;
  if (e < N_EDGES) atomicAdd(&cnt[dst[e]], 1);
}

#define SCAN_B 512
#define SCAN_NB ((N_NODES + SCAN_B - 1) / SCAN_B)   // 98

__global__ __launch_bounds__(SCAN_B) void k_scan_blocks(const int* __restrict__ deg,
                                                        int* __restrict__ excl,
                                                        int* __restrict__ partial) {
  __shared__ int buf[SCAN_B];
  int t = threadIdx.x;
  int i = blockIdx.x * SCAN_B + t;
  int v = (i < N_NODES) ? deg[i] : 0;
  buf[t] = v;
  __syncthreads();
  for (int off = 1; off < SCAN_B; off <<= 1) {
    int x = (t >= off) ? buf[t - off] : 0;
    __syncthreads();
    buf[t] += x;
    __syncthreads();
  }
  if (i < N_NODES) excl[i] = buf[t] - v;
  if (t == SCAN_B - 1) partial[blockIdx.x] = buf[t];
}

__global__ void k_scan_partials(int* __restrict__ partial, int* __restrict__ rowptr) {
  __shared__ int buf[SCAN_NB];
  int t = threadIdx.x;
  if (t < SCAN_NB) buf[t] = partial[t];
  __syncthreads();
  if (t == 0) {
    int run = 0;
    for (int b = 0; b < SCAN_NB; b++) { int v = buf[b]; buf[b] = run; run += v; }
    rowptr[N_NODES] = run;
  }
  __syncthreads();
  if (t < SCAN_NB) partial[t] = buf[t];
}

__global__ void k_scan_add(int* __restrict__ rowptr, const int* __restrict__ partial) {
  int i = blockIdx.x * blockDim.x + threadIdx.x;
  if (i < N_NODES) rowptr[i] += partial[i / SCAN_B];
}

__global__ void k_scatter(const int* __restrict__ src, const int* __restrict__ dst,
                          const int* __restrict__ rowptr, int* __restrict__ cursor,
                          int* __restrict__ csr_src) {
  int e = blockIdx.x * blockDim.x + threadIdx.x;
  if (e < N_EDGES) {
    int d = dst[e];
    int pos = rowptr[d] + atomicAdd(&cursor[d], 1);
    csr_src[pos] = src[e];
  }
}

// ---------------- weight transpose (+ N padding), dual-dtype source ----------------
// W (raw, flag dtype) is [K][Nsrc]; writes Wt32[Ndst][K] (f32) and optionally Wt16.
__global__ void k_transpose_dual(const void* __restrict__ W, float* __restrict__ Wt32,
                                 __hip_bfloat16* __restrict__ Wt16,
                                 int K, int Nsrc, int Ndst, const int* __restrict__ flag) {
  int isbf = *flag;
  int i = blockIdx.x * blockDim.x + threadIdx.x;
  if (i >= Ndst * K) return;
  int n = i / K, k = i - n * K;
  float v = 0.f;
  if (n < Nsrc) v = ldflag(W, (long long)k * Nsrc + n, isbf);
  Wt32[(size_t)n * K + k] = v;
  if (Wt16) Wt16[(size_t)n * K + k] = __float2bfloat16(v);
}

// ---------------- fp32 vector GEMM: C[M][N] = A[M][K] * Bt[N][K]^T ----------------
// 64x64 tile, 256 threads, thread computes 4x4, Kstep 16. Runs iff want<0 || *flag==want.
__global__ __launch_bounds__(256) void k_gemm_f32(const float* __restrict__ A,
                                                  const float* __restrict__ Bt,
                                                  float* __restrict__ C,
                                                  int M, int K, int N,
                                                  const int* __restrict__ flag, int want) {
  if (want >= 0 && *flag != want) return;
  __shared__ float As[64][17];
  __shared__ float Bs[64][17];
  int t = threadIdx.x;
  int m0 = blockIdx.x * 64, n0 = blockIdx.y * 64;
  int lc = t & 15, lr = t >> 4;          // loader: col 0..15, row 0..15 (+16*s)
  int tx = t & 15, ty = t >> 4;          // compute: 4 cols per tx, 4 rows per ty
  float acc[4][4] = {};
  for (int k0 = 0; k0 < K; k0 += 16) {
    float av[4], bv[4];
    #pragma unroll
    for (int s = 0; s < 4; s++) {
      int row = lr + s * 16;
      int gm = m0 + row;
      av[s] = (gm < M) ? A[(size_t)gm * K + k0 + lc] : 0.f;
      bv[s] = Bt[(size_t)(n0 + row) * K + k0 + lc];
    }
    __syncthreads();
    #pragma unroll
    for (int s = 0; s < 4; s++) {
      int row = lr + s * 16;
      As[row][lc] = av[s];
      Bs[row][lc] = bv[s];
    }
    __syncthreads();
    #pragma unroll
    for (int kk = 0; kk < 16; kk++) {
      float a[4], b[4];
      #pragma unroll
      for (int i = 0; i < 4; i++) a[i] = As[ty * 4 + i][kk];
      #pragma unroll
      for (int j = 0; j < 4; j++) b[j] = Bs[tx * 4 + j][kk];
      #pragma unroll
      for (int i = 0; i < 4; i++)
        #pragma unroll
        for (int j = 0; j < 4; j++)
          acc[i][j] += a[i] * b[j];
    }
  }
  #pragma unroll
  for (int i = 0; i < 4; i++) {
    int gm = m0 + ty * 4 + i;
    if (gm < M)
      #pragma unroll
      for (int j = 0; j < 4; j++)
        C[(size_t)gm * N + n0 + tx * 4 + j] = acc[i][j];
  }
}

// ---------------- MFMA bf16 GEMM (layer 0, runs iff *flag==1: A raw already bf16) ----------------
__global__ __launch_bounds__(256) void k_gemm_bt16(const __hip_bfloat16* __restrict__ A,
                                                   const __hip_bfloat16* __restrict__ Bt,
                                                   float* __restrict__ C,
                                                   int M, int K, int N,
                                                   const int* __restrict__ flag) {
  if (*flag != 1) return;
  __shared__ unsigned short As[64][40];
  __shared__ unsigned short Bs[64][40];
  int tid = threadIdx.x;
  int m0 = blockIdx.x * 64, n0 = blockIdx.y * 64;
  int lrow = tid >> 2;
  int lcol = (tid & 3) * 8;
  int wave = tid >> 6, lane = tid & 63;
  int wm = (wave >> 1) * 32, wn = (wave & 1) * 32;
  int lm = lane & 15, quad = lane >> 4;
  f32x4 acc[2][2] = {};
  for (int k0 = 0; k0 < K; k0 += 32) {
    int ga = m0 + lrow;
    uint4 av = make_uint4(0u, 0u, 0u, 0u);
    if (ga < M) av = *(const uint4*)(A + (size_t)ga * K + k0 + lcol);
    uint4 bv = *(const uint4*)(Bt + (size_t)(n0 + lrow) * K + k0 + lcol);
    __syncthreads();
    *(uint4*)(&As[lrow][lcol]) = av;
    *(uint4*)(&Bs[lrow][lcol]) = bv;
    __syncthreads();
    bf16x8 af[2], bfr[2];
    #pragma unroll
    for (int i = 0; i < 2; i++) {
      af[i]  = *(const bf16x8*)(&As[wm + i * 16 + lm][quad * 8]);
      bfr[i] = *(const bf16x8*)(&Bs[wn + i * 16 + lm][quad * 8]);
    }
    #pragma unroll
    for (int mi = 0; mi < 2; mi++)
      #pragma unroll
      for (int ni = 0; ni < 2; ni++)
        acc[mi][ni] = __builtin_amdgcn_mfma_f32_16x16x32_bf16(af[mi], bfr[ni], acc[mi][ni], 0, 0, 0);
  }
  #pragma unroll
  for (int mi = 0; mi < 2; mi++)
    #pragma unroll
    for (int ni = 0; ni < 2; ni++)
      #pragma unroll
      for (int r = 0; r < 4; r++) {
        int gm = m0 + wm + mi * 16 + quad * 4 + r;
        int gn = n0 + wn + ni * 16 + lm;
        if (gm < M) C[(size_t)gm * N + gn] = acc[mi][ni][r];
      }
}

// ---------------- el/er: per-(node,head) dot(feat, a) ----------------
__global__ void k_eler(const float* __restrict__ feat,
                       const void* __restrict__ al, const void* __restrict__ ar,
                       float* __restrict__ el, float* __restrict__ er,
                       int H, int D, int rowstride, const int* __restrict__ flag) {
  int isbf = *flag;
  int i = blockIdx.x * blockDim.x + threadIdx.x;
  if (i >= N_NODES * H) return;
  int n = i / H, h = i - n * H;
  const float* f = feat + (size_t)n * rowstride + h * D;
  float sl = 0.f, sr = 0.f;
  for (int d = 0; d < D; d++) {
    float v = f[d];
    int b = h * D + d;
    sl += v * ldflag(al, b, isbf);
    sr += v * ldflag(ar, b, isbf);
  }
  el[i] = sl;
  er[i] = sr;
}

// ---------------- fused edge-softmax + aggregation, 8 heads x 32 dims ----------------
__global__ __launch_bounds__(256) void k_aggregate8(const int* __restrict__ rowptr,
                                                    const int* __restrict__ csr_src,
                                                    const float* __restrict__ feat,
                                                    const float* __restrict__ el,
                                                    const float* __restrict__ er,
                                                    const void* __restrict__ bias,
                                                    float* __restrict__ out,
                                                    const int* __restrict__ flag) {
  int isbf = *flag;
  int n = blockIdx.x;
  int t = threadIdx.x;
  int h = t >> 5;
  float er_n = er[n * HEADS + h];
  int beg = rowptr[n], end = rowptr[n + 1];
  float m = -1e30f, l = 0.f, acc = 0.f;
  float elN = 0.f, fN = 0.f;
  if (beg < end) {
    int s0 = csr_src[beg];
    elN = el[s0 * HEADS + h];
    fN = feat[(size_t)s0 * HID + t];
  }
  for (int i = beg; i < end; i++) {
    float elc = elN, fc = fN;
    if (i + 1 < end) {
      int s2 = csr_src[i + 1];
      elN = el[s2 * HEADS + h];
      fN = feat[(size_t)s2 * HID + t];
    }
    float x = elc + er_n;
    float e = x > 0.f ? x : 0.2f * x;
    float nm = fmaxf(m, e);
    float sc = __expf(m - nm);
    float p = __expf(e - nm);
    l = l * sc + p;
    acc = acc * sc + p * fc;
    m = nm;
  }
  float o = acc / fmaxf(l, 1e-9f) + ldflag(bias, t, isbf);
  o = fmaxf(o, 0.f);
  out[(size_t)n * HID + t] = o;
}

// ---------------- layer 2 aggregate: 1 head x 40 dims, no ReLU, writes d_out ----------------
__global__ __launch_bounds__(64) void k_aggregate1(const int* __restrict__ rowptr,
                                                   const int* __restrict__ csr_src,
                                                   const float* __restrict__ feat2,
                                                   const float* __restrict__ el,
                                                   const float* __restrict__ er,
                                                   const void* __restrict__ bias,
                                                   void* __restrict__ out,
                                                   const int* __restrict__ flag) {
  int isbf = *flag;
  int n = blockIdx.x;
  int t = threadIdx.x;
  float er_n = er[n];
  int beg = rowptr[n], end = rowptr[n + 1];
  float m = -1e30f, l = 0.f, acc = 0.f;
  float elN = 0.f, fN = 0.f;
  if (beg < end) {
    int s0 = csr_src[beg];
    elN = el[s0];
    fN = feat2[(size_t)s0 * NCLS_PAD + t];
  }
  for (int i = beg; i < end; i++) {
    float elc = elN, fc = fN;
    if (i + 1 < end) {
      int s2 = csr_src[i + 1];
      elN = el[s2];
      fN = feat2[(size_t)s2 * NCLS_PAD + t];
    }
    float x = elc + er_n;
    float e = x > 0.f ? x : 0.2f * x;
    float nm = fmaxf(m, e);
    float sc = __expf(m - nm);
    float p = __expf(e - nm);
    l = l * sc + p;
    acc = acc * sc + p * fc;
    m = nm;
  }
  if (t < N_CLS) {
    float o = acc / fmaxf(l, 1e-9f) + ldflag(bias, t, isbf);
    if (isbf) ((__hip_bfloat16*)out)[(size_t)n * N_CLS + t] = __float2bfloat16(o);
    else      ((float*)out)[(size_t)n * N_CLS + t] = o;
  }
}

// ---------------- launch ----------------
static inline size_t align_up(size_t x) { return (x + 255) & ~(size_t)255; }

extern "C" void kernel_launch(void* const* d_in, const int* in_sizes, int n_in,
                              void* d_out, int out_size, void* d_ws, size_t ws_size,
                              hipStream_t stream) {
  const void* in_feat = d_in[0];
  const int* src = (const int*)d_in[1];
  const int* dst = (const int*)d_in[2];
  const void* W0  = d_in[3];
  const void* al0 = d_in[4];
  const void* ar0 = d_in[5];
  const void* b0  = d_in[6];
  const void* W1  = d_in[7];
  const void* al1 = d_in[8];
  const void* ar1 = d_in[9];
  const void* b1  = d_in[10];
  const void* W2  = d_in[11];
  const void* al2 = d_in[12];
  const void* ar2 = d_in[13];
  const void* b2  = d_in[14];

  // workspace carve-up (~110 MB)
  char* p = (char*)d_ws;
  int* flag = (int*)p;                   p += 256;
  int* rowptr = (int*)p;                 p += align_up((N_NODES + 1) * sizeof(int));
  int* cursor = (int*)p;                 p += align_up(N_NODES * sizeof(int));
  int* csr_src = (int*)p;                p += align_up(N_EDGES * sizeof(int));
  int* partial = (int*)p;                p += align_up(SCAN_NB * sizeof(int));
  float* feat = (float*)p;               p += align_up((size_t)N_NODES * HID * sizeof(float));
  float* el = (float*)p;                 p += align_up((size_t)N_NODES * HEADS * sizeof(float));
  float* er = (float*)p;                 p += align_up((size_t)N_NODES * HEADS * sizeof(float));
  float* hnext = (float*)p;              p += align_up((size_t)N_NODES * HID * sizeof(float));
  float* w0t32 = (float*)p;              p += align_up((size_t)HID * IN_F * sizeof(float));
  float* w1t32 = (float*)p;              p += align_up((size_t)HID * HID * sizeof(float));
  float* w2t32 = (float*)p;              p += align_up((size_t)NCLS_PAD * HID * sizeof(float));
  __hip_bfloat16* w0t16 = (__hip_bfloat16*)p; p += align_up((size_t)HID * IN_F * sizeof(__hip_bfloat16));

  const int EB = (N_EDGES + 255) / 256;
  const int MB64 = (N_NODES + 63) / 64;

  // ---- dtype detection ----
  k_detect<<<1, 256, 0, stream>>>((const unsigned short*)in_feat, flag);

  // ---- CSR build ----
  hipMemsetAsync(cursor, 0, N_NODES * sizeof(int), stream);
  k_hist<<<EB, 256, 0, stream>>>(dst, cursor);
  k_scan_blocks<<<SCAN_NB, SCAN_B, 0, stream>>>(cursor, rowptr, partial);
  k_scan_partials<<<1, 128, 0, stream>>>(partial, rowptr);
  k_scan_add<<<(N_NODES + 255) / 256, 256, 0, stream>>>(rowptr, partial);
  hipMemsetAsync(cursor, 0, N_NODES * sizeof(int), stream);
  k_scatter<<<EB, 256, 0, stream>>>(src, dst, rowptr, cursor, csr_src);

  // ---- weight transposes (f32 always; bf16 copy only for layer-0 MFMA path) ----
  k_transpose_dual<<<(HID * IN_F + 255) / 256, 256, 0, stream>>>(W0, w0t32, w0t16, IN_F, HID, HID, flag);
  k_transpose_dual<<<(HID * HID + 255) / 256, 256, 0, stream>>>(W1, w1t32, nullptr, HID, HID, HID, flag);
  k_transpose_dual<<<(NCLS_PAD * HID + 255) / 256, 256, 0, stream>>>(W2, w2t32, nullptr, HID, N_CLS, NCLS_PAD, flag);

  // ---- layer 0: two gated GEMMs, exactly one runs ----
  k_gemm_f32<<<dim3(MB64, HID / 64), 256, 0, stream>>>((const float*)in_feat, w0t32, feat,
                                                       N_NODES, IN_F, HID, flag, 0);
  k_gemm_bt16<<<dim3(MB64, HID / 64), 256, 0, stream>>>((const __hip_bfloat16*)in_feat, w0t16, feat,
                                                        N_NODES, IN_F, HID, flag);
  k_eler<<<(N_NODES * HEADS + 255) / 256, 256, 0, stream>>>(feat, al0, ar0, el, er, HEADS, DHEAD, HID, flag);
  k_aggregate8<<<N_NODES, 256, 0, stream>>>(rowptr, csr_src, feat, el, er, b0, hnext, flag);

  // ---- layer 1 (fp32 GEMM in both modes: h stays f32, matches np reference exactly) ----
  k_gemm_f32<<<dim3(MB64, HID / 64), 256, 0, stream>>>(hnext, w1t32, feat, N_NODES, HID, HID, flag, -1);
  k_eler<<<(N_NODES * HEADS + 255) / 256, 256, 0, stream>>>(feat, al1, ar1, el, er, HEADS, DHEAD, HID, flag);
  k_aggregate8<<<N_NODES, 256, 0, stream>>>(rowptr, csr_src, feat, el, er, b1, hnext, flag);

  // ---- layer 2 ----
  k_gemm_f32<<<dim3(MB64, 1), 256, 0, stream>>>(hnext, w2t32, feat, N_NODES, HID, NCLS_PAD, flag, -1);
  k_eler<<<(N_NODES + 255) / 256, 256, 0, stream>>>(feat, al2, ar2, el, er, 1, N_CLS, NCLS_PAD, flag);
  k_aggregate1<<<N_NODES, 64, 0, stream>>>(rowptr, csr_src, feat, el, er, b2, d_out, flag);
}

// Round 3
// 930.712 us; speedup vs baseline: 1.4365x; 1.4365x over previous
//
#include <hip/hip_runtime.h>
#include <hip/hip_bf16.h>

#define N_NODES 50000
#define N_EDGES 800000
#define IN_F 512
#define HID 256
#define HEADS 8
#define DHEAD 32
#define N_CLS 40
#define NCLS_PAD 64

typedef __bf16 bf16x8 __attribute__((ext_vector_type(8)));
typedef float f32x4 __attribute__((ext_vector_type(4)));

// read element i of a raw array that is bf16 if isbf else f32
__device__ __forceinline__ float ldflag(const void* p, long long i, int isbf) {
  return isbf ? __bfloat162float(((const __hip_bfloat16*)p)[i])
              : ((const float*)p)[i];
}

// ---------------- dtype detection (flag: 1 = bf16 inputs, 0 = f32 inputs) ----------------
__global__ void k_detect(const unsigned short* __restrict__ raw, int* __restrict__ flag) {
  __shared__ int cnt[256];
  int t = threadIdx.x;
  int c = 0;
  for (int i = t; i < 8192; i += 256) {
    int e = (raw[i] >> 7) & 0xFF;
    if (e >= 0x90) c++;
  }
  cnt[t] = c;
  __syncthreads();
  for (int s = 128; s; s >>= 1) {
    if (t < s) cnt[t] += cnt[t + s];
    __syncthreads();
  }
  if (t == 0) *flag = (cnt[0] > 64) ? 0 : 1;
}

// ---------------- cast raw (flag dtype) -> bf16, n % 4 == 0 ----------------
__global__ void k_cast_bf16(const void* __restrict__ in, __hip_bfloat16* __restrict__ out,
                            long long n, const int* __restrict__ flag) {
  int isbf = *flag;
  long long i = (long long)blockIdx.x * blockDim.x + threadIdx.x;
  long long stride = (long long)gridDim.x * blockDim.x;
  long long n4 = n >> 2;
  if (isbf) {
    const ushort4* p4 = (const ushort4*)in;
    ushort4* o4 = (ushort4*)out;
    for (long long j = i; j < n4; j += stride) o4[j] = p4[j];
  } else {
    const float4* p4 = (const float4*)in;
    for (long long j = i; j < n4; j += stride) {
      float4 v = p4[j];
      ushort4 o;
      o.x = __bfloat16_as_ushort(__float2bfloat16(v.x));
      o.y = __bfloat16_as_ushort(__float2bfloat16(v.y));
      o.z = __bfloat16_as_ushort(__float2bfloat16(v.z));
      o.w = __bfloat16_as_ushort(__float2bfloat16(v.w));
      ((ushort4*)out)[j] = o;
    }
  }
}

// ---------------- CSR build (by dst) ----------------
__global__ void k_hist(const int* __restrict__ dst, int* __restrict__ cnt) {
  int e = blockIdx.x * blockDim.x + threadIdx.x;
  if (e < N_EDGES) atomicAdd(&cnt[dst[e]], 1);
}

#define SCAN_B 512
#define SCAN_NB ((N_NODES + SCAN_B - 1) / SCAN_B)   // 98

__global__ __launch_bounds__(SCAN_B) void k_scan_blocks(const int* __restrict__ deg,
                                                        int* __restrict__ excl,
                                                        int* __restrict__ partial) {
  __shared__ int buf[SCAN_B];
  int t = threadIdx.x;
  int i = blockIdx.x * SCAN_B + t;
  int v = (i < N_NODES) ? deg[i] : 0;
  buf[t] = v;
  __syncthreads();
  for (int off = 1; off < SCAN_B; off <<= 1) {
    int x = (t >= off) ? buf[t - off] : 0;
    __syncthreads();
    buf[t] += x;
    __syncthreads();
  }
  if (i < N_NODES) excl[i] = buf[t] - v;
  if (t == SCAN_B - 1) partial[blockIdx.x] = buf[t];
}

__global__ void k_scan_partials(int* __restrict__ partial, int* __restrict__ rowptr) {
  __shared__ int buf[SCAN_NB];
  int t = threadIdx.x;
  if (t < SCAN_NB) buf[t] = partial[t];
  __syncthreads();
  if (t == 0) {
    int run = 0;
    for (int b = 0; b < SCAN_NB; b++) { int v = buf[b]; buf[b] = run; run += v; }
    rowptr[N_NODES] = run;
  }
  __syncthreads();
  if (t < SCAN_NB) partial[t] = buf[t];
}

__global__ void k_scan_add(int* __restrict__ rowptr, const int* __restrict__ partial) {
  int i = blockIdx.x * blockDim.x + threadIdx.x;
  if (i < N_NODES) rowptr[i] += partial[i / SCAN_B];
}

__global__ void k_scatter(const int* __restrict__ src, const int* __restrict__ dst,
                          const int* __restrict__ rowptr, int* __restrict__ cursor,
                          int* __restrict__ csr_src) {
  int e = blockIdx.x * blockDim.x + threadIdx.x;
  if (e < N_EDGES) {
    int d = dst[e];
    int pos = rowptr[d] + atomicAdd(&cursor[d], 1);
    csr_src[pos] = src[e];
  }
}

// ---------------- weight transpose (+ N padding) -> bf16 [Ndst][K] ----------------
__global__ void k_transpose16(const void* __restrict__ W, __hip_bfloat16* __restrict__ Wt,
                              int K, int Nsrc, int Ndst, const int* __restrict__ flag) {
  int isbf = *flag;
  int i = blockIdx.x * blockDim.x + threadIdx.x;
  if (i >= Ndst * K) return;
  int n = i / K, k = i - n * K;
  float v = 0.f;
  if (n < Nsrc) v = ldflag(W, (long long)k * Nsrc + n, isbf);
  Wt[(size_t)n * K + k] = __float2bfloat16(v);
}

// ---------------- MFMA bf16 GEMM: C[M][N] = A[M][K] * Bt[N][K]^T, C bf16 ----------------
// tile 64x64, Kstep 32, 4 waves/block, each wave 32x32 (2x2 of 16x16x32 mfma)
__global__ __launch_bounds__(256) void k_gemm_bt16(const __hip_bfloat16* __restrict__ A,
                                                   const __hip_bfloat16* __restrict__ Bt,
                                                   __hip_bfloat16* __restrict__ C,
                                                   int M, int K, int N) {
  __shared__ unsigned short As[64][40];  // 80 B pitch: 16B-aligned rows, spreads banks
  __shared__ unsigned short Bs[64][40];
  int tid = threadIdx.x;
  int m0 = blockIdx.x * 64, n0 = blockIdx.y * 64;
  int lrow = tid >> 2;
  int lcol = (tid & 3) * 8;
  int wave = tid >> 6, lane = tid & 63;
  int wm = (wave >> 1) * 32, wn = (wave & 1) * 32;
  int lm = lane & 15, quad = lane >> 4;
  f32x4 acc[2][2] = {};
  for (int k0 = 0; k0 < K; k0 += 32) {
    int ga = m0 + lrow;
    uint4 av = make_uint4(0u, 0u, 0u, 0u);
    if (ga < M) av = *(const uint4*)(A + (size_t)ga * K + k0 + lcol);
    uint4 bv = *(const uint4*)(Bt + (size_t)(n0 + lrow) * K + k0 + lcol);
    __syncthreads();
    *(uint4*)(&As[lrow][lcol]) = av;
    *(uint4*)(&Bs[lrow][lcol]) = bv;
    __syncthreads();
    bf16x8 af[2], bfr[2];
    #pragma unroll
    for (int i = 0; i < 2; i++) {
      af[i]  = *(const bf16x8*)(&As[wm + i * 16 + lm][quad * 8]);
      bfr[i] = *(const bf16x8*)(&Bs[wn + i * 16 + lm][quad * 8]);
    }
    #pragma unroll
    for (int mi = 0; mi < 2; mi++)
      #pragma unroll
      for (int ni = 0; ni < 2; ni++)
        acc[mi][ni] = __builtin_amdgcn_mfma_f32_16x16x32_bf16(af[mi], bfr[ni], acc[mi][ni], 0, 0, 0);
  }
  // C/D layout: col = lane&15, row = quad*4 + r  (m89/m91 verified)
  #pragma unroll
  for (int mi = 0; mi < 2; mi++)
    #pragma unroll
    for (int ni = 0; ni < 2; ni++)
      #pragma unroll
      for (int r = 0; r < 4; r++) {
        int gm = m0 + wm + mi * 16 + quad * 4 + r;
        int gn = n0 + wn + ni * 16 + lm;
        if (gm < M) C[(size_t)gm * N + gn] = __float2bfloat16(acc[mi][ni][r]);
      }
}

// ---------------- el/er: per-(node,head) dot(feat, a), feat bf16 ----------------
__global__ void k_eler(const __hip_bfloat16* __restrict__ feat,
                       const void* __restrict__ al, const void* __restrict__ ar,
                       float* __restrict__ el, float* __restrict__ er,
                       int H, int D, int rowstride, const int* __restrict__ flag) {
  int isbf = *flag;
  int i = blockIdx.x * blockDim.x + threadIdx.x;
  if (i >= N_NODES * H) return;
  int n = i / H, h = i - n * H;
  const __hip_bfloat16* f = feat + (size_t)n * rowstride + h * D;
  float sl = 0.f, sr = 0.f;
  for (int d = 0; d < D; d++) {
    float v = __bfloat162float(f[d]);
    int b = h * D + d;
    sl += v * ldflag(al, b, isbf);
    sr += v * ldflag(ar, b, isbf);
  }
  el[i] = sl;
  er[i] = sr;
}

// ---------------- fused edge-softmax + aggregation, 8 heads x 32 dims ----------------
// one block (256 thr) per dst node; thread t owns channel t (h=t>>5); ReLU + bf16 out
__global__ __launch_bounds__(256) void k_aggregate8(const int* __restrict__ rowptr,
                                                    const int* __restrict__ csr_src,
                                                    const __hip_bfloat16* __restrict__ feat,
                                                    const float* __restrict__ el,
                                                    const float* __restrict__ er,
                                                    const void* __restrict__ bias,
                                                    __hip_bfloat16* __restrict__ out,
                                                    const int* __restrict__ flag) {
  int isbf = *flag;
  int n = blockIdx.x;
  int t = threadIdx.x;
  int h = t >> 5;
  float er_n = er[n * HEADS + h];
  int beg = rowptr[n], end = rowptr[n + 1];
  float m = -1e30f, l = 0.f, acc = 0.f;
  float elN = 0.f, fN = 0.f;
  if (beg < end) {
    int s0 = csr_src[beg];
    elN = el[s0 * HEADS + h];
    fN = __bfloat162float(feat[(size_t)s0 * HID + t]);
  }
  for (int i = beg; i < end; i++) {
    float elc = elN, fc = fN;
    if (i + 1 < end) {                       // value-prefetch next edge
      int s2 = csr_src[i + 1];
      elN = el[s2 * HEADS + h];
      fN = __bfloat162float(feat[(size_t)s2 * HID + t]);
    }
    float x = elc + er_n;
    float e = x > 0.f ? x : 0.2f * x;        // leaky_relu
    float nm = fmaxf(m, e);
    float sc = __expf(m - nm);
    float p = __expf(e - nm);
    l = l * sc + p;
    acc = acc * sc + p * fc;
    m = nm;
  }
  float o = acc / fmaxf(l, 1e-9f) + ldflag(bias, t, isbf);
  o = fmaxf(o, 0.f);                         // ReLU (layers 0,1)
  out[(size_t)n * HID + t] = __float2bfloat16(o);
}

// ---------------- layer 2: 1 head x 40 dims, no ReLU, writes d_out (flag dtype) ----------------
__global__ __launch_bounds__(64) void k_aggregate1(const int* __restrict__ rowptr,
                                                   const int* __restrict__ csr_src,
                                                   const __hip_bfloat16* __restrict__ feat2,
                                                   const float* __restrict__ el,
                                                   const float* __restrict__ er,
                                                   const void* __restrict__ bias,
                                                   void* __restrict__ out,
                                                   const int* __restrict__ flag) {
  int isbf = *flag;
  int n = blockIdx.x;
  int t = threadIdx.x;   // 0..63, channels 0..39 live (cols 40..63 exact zeros)
  float er_n = er[n];
  int beg = rowptr[n], end = rowptr[n + 1];
  float m = -1e30f, l = 0.f, acc = 0.f;
  float elN = 0.f, fN = 0.f;
  if (beg < end) {
    int s0 = csr_src[beg];
    elN = el[s0];
    fN = __bfloat162float(feat2[(size_t)s0 * NCLS_PAD + t]);
  }
  for (int i = beg; i < end; i++) {
    float elc = elN, fc = fN;
    if (i + 1 < end) {
      int s2 = csr_src[i + 1];
      elN = el[s2];
      fN = __bfloat162float(feat2[(size_t)s2 * NCLS_PAD + t]);
    }
    float x = elc + er_n;
    float e = x > 0.f ? x : 0.2f * x;
    float nm = fmaxf(m, e);
    float sc = __expf(m - nm);
    float p = __expf(e - nm);
    l = l * sc + p;
    acc = acc * sc + p * fc;
    m = nm;
  }
  if (t < N_CLS) {
    float o = acc / fmaxf(l, 1e-9f) + ldflag(bias, t, isbf);
    if (isbf) ((__hip_bfloat16*)out)[(size_t)n * N_CLS + t] = __float2bfloat16(o);
    else      ((float*)out)[(size_t)n * N_CLS + t] = o;
  }
}

// ---------------- launch ----------------
static inline size_t align_up(size_t x) { return (x + 255) & ~(size_t)255; }

extern "C" void kernel_launch(void* const* d_in, const int* in_sizes, int n_in,
                              void* d_out, int out_size, void* d_ws, size_t ws_size,
                              hipStream_t stream) {
  const void* in_feat = d_in[0];
  const int* src = (const int*)d_in[1];
  const int* dst = (const int*)d_in[2];
  const void* W0  = d_in[3];
  const void* al0 = d_in[4];
  const void* ar0 = d_in[5];
  const void* b0  = d_in[6];
  const void* W1  = d_in[7];
  const void* al1 = d_in[8];
  const void* ar1 = d_in[9];
  const void* b1  = d_in[10];
  const void* W2  = d_in[11];
  const void* al2 = d_in[12];
  const void* ar2 = d_in[13];
  const void* b2  = d_in[14];

  // workspace carve-up (~110 MB)
  char* p = (char*)d_ws;
  int* flag = (int*)p;                   p += 256;
  int* rowptr = (int*)p;                 p += align_up((N_NODES + 1) * sizeof(int));
  int* cursor = (int*)p;                 p += align_up(N_NODES * sizeof(int));
  int* csr_src = (int*)p;                p += align_up(N_EDGES * sizeof(int));
  int* partial = (int*)p;                p += align_up(SCAN_NB * sizeof(int));
  __hip_bfloat16* a16 = (__hip_bfloat16*)p;   p += align_up((size_t)N_NODES * IN_F * sizeof(__hip_bfloat16));
  __hip_bfloat16* feat16 = (__hip_bfloat16*)p; p += align_up((size_t)N_NODES * HID * sizeof(__hip_bfloat16));
  __hip_bfloat16* h16 = (__hip_bfloat16*)p;    p += align_up((size_t)N_NODES * HID * sizeof(__hip_bfloat16));
  float* el = (float*)p;                 p += align_up((size_t)N_NODES * HEADS * sizeof(float));
  float* er = (float*)p;                 p += align_up((size_t)N_NODES * HEADS * sizeof(float));
  __hip_bfloat16* w0t = (__hip_bfloat16*)p;   p += align_up((size_t)HID * IN_F * sizeof(__hip_bfloat16));
  __hip_bfloat16* w1t = (__hip_bfloat16*)p;   p += align_up((size_t)HID * HID * sizeof(__hip_bfloat16));
  __hip_bfloat16* w2t = (__hip_bfloat16*)p;   p += align_up((size_t)NCLS_PAD * HID * sizeof(__hip_bfloat16));

  const int EB = (N_EDGES + 255) / 256;
  const int MB64 = (N_NODES + 63) / 64;

  // ---- dtype detection ----
  k_detect<<<1, 256, 0, stream>>>((const unsigned short*)in_feat, flag);

  // ---- CSR build ----
  hipMemsetAsync(cursor, 0, N_NODES * sizeof(int), stream);
  k_hist<<<EB, 256, 0, stream>>>(dst, cursor);
  k_scan_blocks<<<SCAN_NB, SCAN_B, 0, stream>>>(cursor, rowptr, partial);
  k_scan_partials<<<1, 128, 0, stream>>>(partial, rowptr);
  k_scan_add<<<(N_NODES + 255) / 256, 256, 0, stream>>>(rowptr, partial);
  hipMemsetAsync(cursor, 0, N_NODES * sizeof(int), stream);
  k_scatter<<<EB, 256, 0, stream>>>(src, dst, rowptr, cursor, csr_src);

  // ---- input cast + weight transposes (all -> bf16) ----
  k_cast_bf16<<<1024, 256, 0, stream>>>(in_feat, a16, (long long)N_NODES * IN_F, flag);
  k_transpose16<<<(HID * IN_F + 255) / 256, 256, 0, stream>>>(W0, w0t, IN_F, HID, HID, flag);
  k_transpose16<<<(HID * HID + 255) / 256, 256, 0, stream>>>(W1, w1t, HID, HID, HID, flag);
  k_transpose16<<<(NCLS_PAD * HID + 255) / 256, 256, 0, stream>>>(W2, w2t, HID, N_CLS, NCLS_PAD, flag);

  // ---- layer 0 ----
  k_gemm_bt16<<<dim3(MB64, HID / 64), 256, 0, stream>>>(a16, w0t, feat16, N_NODES, IN_F, HID);
  k_eler<<<(N_NODES * HEADS + 255) / 256, 256, 0, stream>>>(feat16, al0, ar0, el, er, HEADS, DHEAD, HID, flag);
  k_aggregate8<<<N_NODES, 256, 0, stream>>>(rowptr, csr_src, feat16, el, er, b0, h16, flag);

  // ---- layer 1 ----
  k_gemm_bt16<<<dim3(MB64, HID / 64), 256, 0, stream>>>(h16, w1t, feat16, N_NODES, HID, HID);
  k_eler<<<(N_NODES * HEADS + 255) / 256, 256, 0, stream>>>(feat16, al1, ar1, el, er, HEADS, DHEAD, HID, flag);
  k_aggregate8<<<N_NODES, 256, 0, stream>>>(rowptr, csr_src, feat16, el, er, b1, h16, flag);

  // ---- layer 2 (feat16 reused as [N][64] padded feat2) ----
  k_gemm_bt16<<<dim3(MB64, 1), 256, 0, stream>>>(h16, w2t, feat16, N_NODES, HID, NCLS_PAD);
  k_eler<<<(N_NODES + 255) / 256, 256, 0, stream>>>(feat16, al2, ar2, el, er, 1, N_CLS, NCLS_PAD, flag);
  k_aggregate1<<<N_NODES, 64, 0, stream>>>(rowptr, csr_src, feat16, el, er, b2, d_out, flag);
}

// Round 4
// 586.472 us; speedup vs baseline: 2.2798x; 1.5870x over previous
//
#include <hip/hip_runtime.h>
#include <hip/hip_bf16.h>

#define N_NODES 50000
#define N_EDGES 800000
#define IN_F 512
#define HID 256
#define HEADS 8
#define DHEAD 32
#define N_CLS 40
#define NCLS_PAD 64

typedef __bf16 bf16x8 __attribute__((ext_vector_type(8)));
typedef float f32x4 __attribute__((ext_vector_type(4)));

// f32 att/bias workspace layout (in floats)
#define AT_AL0 0
#define AT_AR0 256
#define AT_AL1 512
#define AT_AR1 768
#define AT_AL2 1024
#define AT_AR2 1088
#define AT_B0  1152
#define AT_B1  1408
#define AT_B2  1664
#define AT_SZ  1792

// read element i of a raw array that is bf16 if isbf else f32
__device__ __forceinline__ float ldflag(const void* p, long long i, int isbf) {
  return isbf ? __bfloat162float(((const __hip_bfloat16*)p)[i])
              : ((const float*)p)[i];
}
// unpack a packed bf16 pair (u32): low-address element in low 16 bits
__device__ __forceinline__ float blo(unsigned u) { return __uint_as_float(u << 16); }
__device__ __forceinline__ float bhi(unsigned u) { return __uint_as_float(u & 0xffff0000u); }

// ---------------- dtype detection (flag: 1 = bf16 inputs, 0 = f32 inputs) ----------------
__global__ void k_detect(const unsigned short* __restrict__ raw, int* __restrict__ flag) {
  __shared__ int cnt[256];
  int t = threadIdx.x;
  int c = 0;
  for (int i = t; i < 8192; i += 256) {
    int e = (raw[i] >> 7) & 0xFF;
    if (e >= 0x90) c++;
  }
  cnt[t] = c;
  __syncthreads();
  for (int s = 128; s; s >>= 1) {
    if (t < s) cnt[t] += cnt[t + s];
    __syncthreads();
  }
  if (t == 0) *flag = (cnt[0] > 64) ? 0 : 1;
}

// ---------------- materialize f32 copies of attention vectors + biases ----------------
__global__ void k_prep(const void* al0, const void* ar0, const void* al1, const void* ar1,
                       const void* al2, const void* ar2, const void* b0, const void* b1,
                       const void* b2, float* __restrict__ att, const int* __restrict__ flag) {
  int isbf = *flag;
  int t = threadIdx.x;   // 256 threads, 1 block
  att[AT_AL0 + t] = ldflag(al0, t, isbf);
  att[AT_AR0 + t] = ldflag(ar0, t, isbf);
  att[AT_AL1 + t] = ldflag(al1, t, isbf);
  att[AT_AR1 + t] = ldflag(ar1, t, isbf);
  att[AT_B0 + t]  = ldflag(b0, t, isbf);
  att[AT_B1 + t]  = ldflag(b1, t, isbf);
  if (t < N_CLS) {
    att[AT_AL2 + t] = ldflag(al2, t, isbf);
    att[AT_AR2 + t] = ldflag(ar2, t, isbf);
    att[AT_B2 + t]  = ldflag(b2, t, isbf);
  }
}

// ---------------- cast raw (flag dtype) -> bf16, n % 4 == 0 ----------------
__global__ void k_cast_bf16(const void* __restrict__ in, __hip_bfloat16* __restrict__ out,
                            long long n, const int* __restrict__ flag) {
  int isbf = *flag;
  long long i = (long long)blockIdx.x * blockDim.x + threadIdx.x;
  long long stride = (long long)gridDim.x * blockDim.x;
  long long n4 = n >> 2;
  if (isbf) {
    const ushort4* p4 = (const ushort4*)in;
    ushort4* o4 = (ushort4*)out;
    for (long long j = i; j < n4; j += stride) o4[j] = p4[j];
  } else {
    const float4* p4 = (const float4*)in;
    for (long long j = i; j < n4; j += stride) {
      float4 v = p4[j];
      ushort4 o;
      o.x = __bfloat16_as_ushort(__float2bfloat16(v.x));
      o.y = __bfloat16_as_ushort(__float2bfloat16(v.y));
      o.z = __bfloat16_as_ushort(__float2bfloat16(v.z));
      o.w = __bfloat16_as_ushort(__float2bfloat16(v.w));
      ((ushort4*)out)[j] = o;
    }
  }
}

// ---------------- CSR build (by dst) ----------------
__global__ void k_hist(const int* __restrict__ dst, int* __restrict__ cnt) {
  int e = blockIdx.x * blockDim.x + threadIdx.x;
  if (e < N_EDGES) atomicAdd(&cnt[dst[e]], 1);
}

#define SCAN_B 512
#define SCAN_NB ((N_NODES + SCAN_B - 1) / SCAN_B)   // 98

__global__ __launch_bounds__(SCAN_B) void k_scan_blocks(const int* __restrict__ deg,
                                                        int* __restrict__ excl,
                                                        int* __restrict__ partial) {
  __shared__ int buf[SCAN_B];
  int t = threadIdx.x;
  int i = blockIdx.x * SCAN_B + t;
  int v = (i < N_NODES) ? deg[i] : 0;
  buf[t] = v;
  __syncthreads();
  for (int off = 1; off < SCAN_B; off <<= 1) {
    int x = (t >= off) ? buf[t - off] : 0;
    __syncthreads();
    buf[t] += x;
    __syncthreads();
  }
  if (i < N_NODES) excl[i] = buf[t] - v;
  if (t == SCAN_B - 1) partial[blockIdx.x] = buf[t];
}

__global__ void k_scan_partials(int* __restrict__ partial, int* __restrict__ rowptr) {
  __shared__ int buf[SCAN_NB];
  int t = threadIdx.x;
  if (t < SCAN_NB) buf[t] = partial[t];
  __syncthreads();
  if (t == 0) {
    int run = 0;
    for (int b = 0; b < SCAN_NB; b++) { int v = buf[b]; buf[b] = run; run += v; }
    rowptr[N_NODES] = run;
  }
  __syncthreads();
  if (t < SCAN_NB) partial[t] = buf[t];
}

__global__ void k_scan_add(int* __restrict__ rowptr, const int* __restrict__ partial) {
  int i = blockIdx.x * blockDim.x + threadIdx.x;
  if (i < N_NODES) rowptr[i] += partial[i / SCAN_B];
}

__global__ void k_scatter(const int* __restrict__ src, const int* __restrict__ dst,
                          const int* __restrict__ rowptr, int* __restrict__ cursor,
                          int* __restrict__ csr_src) {
  int e = blockIdx.x * blockDim.x + threadIdx.x;
  if (e < N_EDGES) {
    int d = dst[e];
    int pos = rowptr[d] + atomicAdd(&cursor[d], 1);
    csr_src[pos] = src[e];
  }
}

// ---------------- weight transpose (+ N padding) -> bf16 [Ndst][K] ----------------
__global__ void k_transpose16(const void* __restrict__ W, __hip_bfloat16* __restrict__ Wt,
                              int K, int Nsrc, int Ndst, const int* __restrict__ flag) {
  int isbf = *flag;
  int i = blockIdx.x * blockDim.x + threadIdx.x;
  if (i >= Ndst * K) return;
  int n = i / K, k = i - n * K;
  float v = 0.f;
  if (n < Nsrc) v = ldflag(W, (long long)k * Nsrc + n, isbf);
  Wt[(size_t)n * K + k] = __float2bfloat16(v);
}

// ---------------- MFMA bf16 GEMM: C[M][N] = A[M][K] * Bt[N][K]^T, C bf16 ----------------
__global__ __launch_bounds__(256) void k_gemm_bt16(const __hip_bfloat16* __restrict__ A,
                                                   const __hip_bfloat16* __restrict__ Bt,
                                                   __hip_bfloat16* __restrict__ C,
                                                   int M, int K, int N) {
  __shared__ unsigned short As[64][40];
  __shared__ unsigned short Bs[64][40];
  int tid = threadIdx.x;
  int m0 = blockIdx.x * 64, n0 = blockIdx.y * 64;
  int lrow = tid >> 2;
  int lcol = (tid & 3) * 8;
  int wave = tid >> 6, lane = tid & 63;
  int wm = (wave >> 1) * 32, wn = (wave & 1) * 32;
  int lm = lane & 15, quad = lane >> 4;
  f32x4 acc[2][2] = {};
  for (int k0 = 0; k0 < K; k0 += 32) {
    int ga = m0 + lrow;
    uint4 av = make_uint4(0u, 0u, 0u, 0u);
    if (ga < M) av = *(const uint4*)(A + (size_t)ga * K + k0 + lcol);
    uint4 bv = *(const uint4*)(Bt + (size_t)(n0 + lrow) * K + k0 + lcol);
    __syncthreads();
    *(uint4*)(&As[lrow][lcol]) = av;
    *(uint4*)(&Bs[lrow][lcol]) = bv;
    __syncthreads();
    bf16x8 af[2], bfr[2];
    #pragma unroll
    for (int i = 0; i < 2; i++) {
      af[i]  = *(const bf16x8*)(&As[wm + i * 16 + lm][quad * 8]);
      bfr[i] = *(const bf16x8*)(&Bs[wn + i * 16 + lm][quad * 8]);
    }
    #pragma unroll
    for (int mi = 0; mi < 2; mi++)
      #pragma unroll
      for (int ni = 0; ni < 2; ni++)
        acc[mi][ni] = __builtin_amdgcn_mfma_f32_16x16x32_bf16(af[mi], bfr[ni], acc[mi][ni], 0, 0, 0);
  }
  #pragma unroll
  for (int mi = 0; mi < 2; mi++)
    #pragma unroll
    for (int ni = 0; ni < 2; ni++)
      #pragma unroll
      for (int r = 0; r < 4; r++) {
        int gm = m0 + wm + mi * 16 + quad * 4 + r;
        int gn = n0 + wn + ni * 16 + lm;
        if (gm < M) C[(size_t)gm * N + gn] = __float2bfloat16(acc[mi][ni][r]);
      }
}

// ---------------- el/er for HID=256/HEADS=8 layers: vectorized 16B/lane ----------------
__global__ void k_eler8(const uint4* __restrict__ feat_rows,   // [N][32] uint4
                        const float* __restrict__ al, const float* __restrict__ ar,
                        float* __restrict__ el, float* __restrict__ er) {
  int i = blockIdx.x * blockDim.x + threadIdx.x;   // (n,h)
  if (i >= N_NODES * HEADS) return;
  int n = i >> 3, h = i & 7;
  const uint4* base = feat_rows + (size_t)n * 32 + h * 4;
  const float* alh = al + h * DHEAD;
  const float* arh = ar + h * DHEAD;
  float sl = 0.f, sr = 0.f;
  #pragma unroll
  for (int q = 0; q < 4; q++) {
    uint4 v = base[q];
    unsigned u[4] = {v.x, v.y, v.z, v.w};
    #pragma unroll
    for (int w = 0; w < 4; w++) {
      int d = q * 8 + w * 2;
      float f0 = blo(u[w]), f1 = bhi(u[w]);
      sl += f0 * alh[d] + f1 * alh[d + 1];
      sr += f0 * arh[d] + f1 * arh[d + 1];
    }
  }
  el[i] = sl;
  er[i] = sr;
}

// ---------------- el/er for layer 2 (1 head, 40 dims, stride 64) ----------------
__global__ void k_eler2(const __hip_bfloat16* __restrict__ feat2,
                        const float* __restrict__ al, const float* __restrict__ ar,
                        float* __restrict__ el, float* __restrict__ er) {
  int n = blockIdx.x * blockDim.x + threadIdx.x;
  if (n >= N_NODES) return;
  const __hip_bfloat16* f = feat2 + (size_t)n * NCLS_PAD;
  float sl = 0.f, sr = 0.f;
  for (int d = 0; d < N_CLS; d++) {
    float v = __bfloat162float(f[d]);
    sl += v * al[d];
    sr += v * ar[d];
  }
  el[n] = sl;
  er[n] = sr;
}

// ---------------- fused edge-softmax + aggregation, vectorized ----------------
// block = 256 thr per dst node = 8 edge-slots x 32 lanes; lane owns 8 channels (uint4).
// No max-subtraction: logits el+er ~ N(0,~2), exp safe in f32 (clamped at 60);
// alpha is shift-invariant so result matches reference. Merge = plain LDS sum.
__global__ __launch_bounds__(256) void k_aggregate8(const int* __restrict__ rowptr,
                                                    const int* __restrict__ csr_src,
                                                    const uint4* __restrict__ feat_rows,
                                                    const float* __restrict__ el,
                                                    const float* __restrict__ er,
                                                    const float* __restrict__ bias,
                                                    __hip_bfloat16* __restrict__ out) {
  __shared__ float lds_acc[8][256];
  __shared__ float lds_l[8][32];
  int n = blockIdx.x;
  int t = threadIdx.x;
  int slot = t >> 5;      // 0..7
  int c = t & 31;         // channel group: channels c*8..c*8+7
  int hh = c >> 2;        // head of this group
  float er_n = er[n * HEADS + hh];
  int beg = rowptr[n], end = rowptr[n + 1];
  float l = 0.f;
  float acc[8] = {0.f, 0.f, 0.f, 0.f, 0.f, 0.f, 0.f, 0.f};
  for (int i = beg + slot; i < end; i += 8) {
    int s = csr_src[i];
    float elv = el[s * HEADS + hh];
    uint4 fv = feat_rows[(size_t)s * 32 + c];
    float x = elv + er_n;
    float e = x > 0.f ? x : 0.2f * x;          // leaky_relu
    float p = __expf(fminf(e, 60.f));
    l += p;
    acc[0] += p * blo(fv.x); acc[1] += p * bhi(fv.x);
    acc[2] += p * blo(fv.y); acc[3] += p * bhi(fv.y);
    acc[4] += p * blo(fv.z); acc[5] += p * bhi(fv.z);
    acc[6] += p * blo(fv.w); acc[7] += p * bhi(fv.w);
  }
  *(float4*)&lds_acc[slot][c * 8]     = make_float4(acc[0], acc[1], acc[2], acc[3]);
  *(float4*)&lds_acc[slot][c * 8 + 4] = make_float4(acc[4], acc[5], acc[6], acc[7]);
  lds_l[slot][c] = l;
  __syncthreads();
  // role 2: thread t = output channel
  float a = 0.f, L = 0.f;
  #pragma unroll
  for (int s2 = 0; s2 < 8; s2++) { a += lds_acc[s2][t]; L += lds_l[s2][t >> 3]; }
  float o = a / fmaxf(L, 1e-9f) + bias[t];
  o = fmaxf(o, 0.f);                            // ReLU (layers 0,1)
  out[(size_t)n * HID + t] = __float2bfloat16(o);
}

// ---------------- layer 2 aggregate: 32 slots x 8 lanes (64-ch padded rows) ----------------
__global__ __launch_bounds__(256) void k_aggregate1(const int* __restrict__ rowptr,
                                                    const int* __restrict__ csr_src,
                                                    const uint4* __restrict__ fr2,  // [N][8] uint4
                                                    const float* __restrict__ el,
                                                    const float* __restrict__ er,
                                                    const float* __restrict__ bias,
                                                    void* __restrict__ out,
                                                    const int* __restrict__ flag) {
  __shared__ float lds_acc[32][64];
  __shared__ float lds_l[32][8];
  int isbf = *flag;
  int n = blockIdx.x;
  int t = threadIdx.x;
  int slot = t >> 3;      // 0..31
  int c = t & 7;          // channels c*8..c*8+7 of 64 (40 live)
  float er_n = er[n];
  int beg = rowptr[n], end = rowptr[n + 1];
  float l = 0.f;
  float acc[8] = {0.f, 0.f, 0.f, 0.f, 0.f, 0.f, 0.f, 0.f};
  for (int i = beg + slot; i < end; i += 32) {
    int s = csr_src[i];
    float x = el[s] + er_n;
    uint4 fv = fr2[(size_t)s * 8 + c];
    float e = x > 0.f ? x : 0.2f * x;
    float p = __expf(fminf(e, 60.f));
    l += p;
    acc[0] += p * blo(fv.x); acc[1] += p * bhi(fv.x);
    acc[2] += p * blo(fv.y); acc[3] += p * bhi(fv.y);
    acc[4] += p * blo(fv.z); acc[5] += p * bhi(fv.z);
    acc[6] += p * blo(fv.w); acc[7] += p * bhi(fv.w);
  }
  *(float4*)&lds_acc[slot][c * 8]     = make_float4(acc[0], acc[1], acc[2], acc[3]);
  *(float4*)&lds_acc[slot][c * 8 + 4] = make_float4(acc[4], acc[5], acc[6], acc[7]);
  lds_l[slot][c] = l;
  __syncthreads();
  if (t < N_CLS) {
    float a = 0.f, L = 0.f;
    #pragma unroll
    for (int s2 = 0; s2 < 32; s2++) { a += lds_acc[s2][t]; L += lds_l[s2][t >> 3]; }
    float o = a / fmaxf(L, 1e-9f) + bias[t];    // no ReLU on output layer
    if (isbf) ((__hip_bfloat16*)out)[(size_t)n * N_CLS + t] = __float2bfloat16(o);
    else      ((float*)out)[(size_t)n * N_CLS + t] = o;
  }
}

// ---------------- launch ----------------
static inline size_t align_up(size_t x) { return (x + 255) & ~(size_t)255; }

extern "C" void kernel_launch(void* const* d_in, const int* in_sizes, int n_in,
                              void* d_out, int out_size, void* d_ws, size_t ws_size,
                              hipStream_t stream) {
  const void* in_feat = d_in[0];
  const int* src = (const int*)d_in[1];
  const int* dst = (const int*)d_in[2];
  const void* W0  = d_in[3];
  const void* al0 = d_in[4];
  const void* ar0 = d_in[5];
  const void* b0  = d_in[6];
  const void* W1  = d_in[7];
  const void* al1 = d_in[8];
  const void* ar1 = d_in[9];
  const void* b1  = d_in[10];
  const void* W2  = d_in[11];
  const void* al2 = d_in[12];
  const void* ar2 = d_in[13];
  const void* b2  = d_in[14];

  char* p = (char*)d_ws;
  int* flag = (int*)p;                   p += 256;
  float* att = (float*)p;                p += align_up(AT_SZ * sizeof(float));
  int* rowptr = (int*)p;                 p += align_up((N_NODES + 1) * sizeof(int));
  int* cursor = (int*)p;                 p += align_up(N_NODES * sizeof(int));
  int* csr_src = (int*)p;                p += align_up(N_EDGES * sizeof(int));
  int* partial = (int*)p;                p += align_up(SCAN_NB * sizeof(int));
  __hip_bfloat16* a16 = (__hip_bfloat16*)p;    p += align_up((size_t)N_NODES * IN_F * sizeof(__hip_bfloat16));
  __hip_bfloat16* feat16 = (__hip_bfloat16*)p; p += align_up((size_t)N_NODES * HID * sizeof(__hip_bfloat16));
  __hip_bfloat16* h16 = (__hip_bfloat16*)p;    p += align_up((size_t)N_NODES * HID * sizeof(__hip_bfloat16));
  float* el = (float*)p;                 p += align_up((size_t)N_NODES * HEADS * sizeof(float));
  float* er = (float*)p;                 p += align_up((size_t)N_NODES * HEADS * sizeof(float));
  __hip_bfloat16* w0t = (__hip_bfloat16*)p;    p += align_up((size_t)HID * IN_F * sizeof(__hip_bfloat16));
  __hip_bfloat16* w1t = (__hip_bfloat16*)p;    p += align_up((size_t)HID * HID * sizeof(__hip_bfloat16));
  __hip_bfloat16* w2t = (__hip_bfloat16*)p;    p += align_up((size_t)NCLS_PAD * HID * sizeof(__hip_bfloat16));

  const int EB = (N_EDGES + 255) / 256;
  const int MB64 = (N_NODES + 63) / 64;

  // ---- dtype detection + constant prep ----
  k_detect<<<1, 256, 0, stream>>>((const unsigned short*)in_feat, flag);
  k_prep<<<1, 256, 0, stream>>>(al0, ar0, al1, ar1, al2, ar2, b0, b1, b2, att, flag);

  // ---- CSR build ----
  hipMemsetAsync(cursor, 0, N_NODES * sizeof(int), stream);
  k_hist<<<EB, 256, 0, stream>>>(dst, cursor);
  k_scan_blocks<<<SCAN_NB, SCAN_B, 0, stream>>>(cursor, rowptr, partial);
  k_scan_partials<<<1, 128, 0, stream>>>(partial, rowptr);
  k_scan_add<<<(N_NODES + 255) / 256, 256, 0, stream>>>(rowptr, partial);
  hipMemsetAsync(cursor, 0, N_NODES * sizeof(int), stream);
  k_scatter<<<EB, 256, 0, stream>>>(src, dst, rowptr, cursor, csr_src);

  // ---- input cast + weight transposes (all -> bf16) ----
  k_cast_bf16<<<1024, 256, 0, stream>>>(in_feat, a16, (long long)N_NODES * IN_F, flag);
  k_transpose16<<<(HID * IN_F + 255) / 256, 256, 0, stream>>>(W0, w0t, IN_F, HID, HID, flag);
  k_transpose16<<<(HID * HID + 255) / 256, 256, 0, stream>>>(W1, w1t, HID, HID, HID, flag);
  k_transpose16<<<(NCLS_PAD * HID + 255) / 256, 256, 0, stream>>>(W2, w2t, HID, N_CLS, NCLS_PAD, flag);

  // ---- layer 0 ----
  k_gemm_bt16<<<dim3(MB64, HID / 64), 256, 0, stream>>>(a16, w0t, feat16, N_NODES, IN_F, HID);
  k_eler8<<<(N_NODES * HEADS + 255) / 256, 256, 0, stream>>>((const uint4*)feat16, att + AT_AL0, att + AT_AR0, el, er);
  k_aggregate8<<<N_NODES, 256, 0, stream>>>(rowptr, csr_src, (const uint4*)feat16, el, er, att + AT_B0, h16);

  // ---- layer 1 ----
  k_gemm_bt16<<<dim3(MB64, HID / 64), 256, 0, stream>>>(h16, w1t, feat16, N_NODES, HID, HID);
  k_eler8<<<(N_NODES * HEADS + 255) / 256, 256, 0, stream>>>((const uint4*)feat16, att + AT_AL1, att + AT_AR1, el, er);
  k_aggregate8<<<N_NODES, 256, 0, stream>>>(rowptr, csr_src, (const uint4*)feat16, el, er, att + AT_B1, h16);

  // ---- layer 2 (feat16 reused as [N][64] padded feat2) ----
  k_gemm_bt16<<<dim3(MB64, 1), 256, 0, stream>>>(h16, w2t, feat16, N_NODES, HID, NCLS_PAD);
  k_eler2<<<(N_NODES + 255) / 256, 256, 0, stream>>>(feat16, att + AT_AL2, att + AT_AR2, el, er);
  k_aggregate1<<<N_NODES, 256, 0, stream>>>(rowptr, csr_src, (const uint4*)feat16, el, er, att + AT_B2, d_out, flag);
}